// Round 5
// baseline (779.836 us; speedup 1.0000x reference)
//
#include <hip/hip_runtime.h>
#include <hip/hip_bf16.h>
#include <hip/hip_fp16.h>

#define H 128
#define SLOT 32    // per-node out-direction capacity (deg ~ Poisson(6); P(>=32) ~ 7e-14)
#define SLOT2 48   // combined bidirectional capacity (deg ~ Poisson(12); P(>=48) ~ 6e-14)

typedef short s16x8 __attribute__((ext_vector_type(8)));
typedef _Float16 h16x8 __attribute__((ext_vector_type(8)));
typedef float f32x4v __attribute__((ext_vector_type(4)));

__device__ __forceinline__ unsigned short f2bf(float v) {
    __hip_bfloat16 h = __float2bfloat16(v);
    return *reinterpret_cast<unsigned short*>(&h);
}
__device__ __forceinline__ float bf2f(unsigned short u) {
    unsigned int x = ((unsigned int)u) << 16;
    return *reinterpret_cast<float*>(&x);
}
__device__ __forceinline__ unsigned short f2h(float v) {
    __half h = __float2half(v);
    return *reinterpret_cast<unsigned short*>(&h);
}
__device__ __forceinline__ float h2f(unsigned short u) {
    __half h = *reinterpret_cast<__half*>(&u);
    return __half2float(h);
}

// convert 8 packed f16 -> 8 packed bf16 (truncating re-round; used for the lo-plane MFMA)
__device__ __forceinline__ s16x8 h8_to_bf8(s16x8 a) {
    union { s16x8 v; __half2 h[4]; } u; u.v = a;
    union { s16x8 v; unsigned short u[8]; } r;
#pragma unroll
    for (int q = 0; q < 4; ++q) {
        float2 t = __half22float2(u.h[q]);
        r.u[2 * q] = f2bf(t.x);
        r.u[2 * q + 1] = f2bf(t.y);
    }
    return r.v;
}

// f16 MFMA wrapper (bit-cast short8 -> half8)
__device__ __forceinline__ f32x4v mfma_h(s16x8 a, s16x8 b, f32x4v c) {
    h16x8 ha = __builtin_bit_cast(h16x8, a);
    h16x8 hb = __builtin_bit_cast(h16x8, b);
    return __builtin_amdgcn_mfma_f32_16x16x32_f16(ha, hb, c, 0, 0, 0);
}

// packed-fp16 relu: single VOP3P v_pk_max_f16 against +0 (inline const 0)
__device__ __forceinline__ __half2 relu2(__half2 v) {
    unsigned int u = *reinterpret_cast<unsigned int*>(&v);
    unsigned int r;
    asm("v_pk_max_f16 %0, %1, 0" : "=v"(r) : "v"(u));
    return *reinterpret_cast<__half2*>(&r);
}

// packed-fp16 dot2 accumulate into f32: d = a.x*b.x + a.y*b.y + c
__device__ __forceinline__ float fdot2f(__half2 a, __half2 b, float c) {
    unsigned int ua = *reinterpret_cast<unsigned int*>(&a);
    unsigned int ub = *reinterpret_cast<unsigned int*>(&b);
    float r;
    asm("v_dot2_f32_f16 %0, %1, %2, %3" : "=v"(r) : "v"(ua), "v"(ub), "v"(c));
    return r;
}

// ---------------- padded-bucket adjacency fill, 4-edge ILP ---------------------
// padj[(s,slot)] = (d,e) for compact; adj2 = unified bidirectional neighbor list.
__global__ void fill_pad_kernel(const int* __restrict__ src, const int* __restrict__ dst,
                                int* __restrict__ cur_o, int* __restrict__ cur2,
                                int2* __restrict__ padj, int* __restrict__ adj2,
                                int E, int quarter) {
    int t = blockIdx.x * blockDim.x + threadIdx.x;
    if (t >= quarter) return;
    int e0 = t, e1 = t + quarter, e2 = t + 2 * quarter, e3 = t + 3 * quarter;
    bool v1 = e1 < E, v2 = e2 < E, v3 = e3 < E;
    int s0 = src[e0], d0 = dst[e0];
    int s1 = v1 ? src[e1] : 0, d1 = v1 ? dst[e1] : 0;
    int s2 = v2 ? src[e2] : 0, d2 = v2 ? dst[e2] : 0;
    int s3 = v3 ? src[e3] : 0, d3 = v3 ? dst[e3] : 0;
    int po0 = atomicAdd(&cur_o[s0], 1);
    int a0 = atomicAdd(&cur2[s0], 1);
    int b0 = atomicAdd(&cur2[d0], 1);
    int po1 = v1 ? atomicAdd(&cur_o[s1], 1) : 0;
    int a1 = v1 ? atomicAdd(&cur2[s1], 1) : 0;
    int b1 = v1 ? atomicAdd(&cur2[d1], 1) : 0;
    int po2 = v2 ? atomicAdd(&cur_o[s2], 1) : 0;
    int a2 = v2 ? atomicAdd(&cur2[s2], 1) : 0;
    int b2 = v2 ? atomicAdd(&cur2[d2], 1) : 0;
    int po3 = v3 ? atomicAdd(&cur_o[s3], 1) : 0;
    int a3 = v3 ? atomicAdd(&cur2[s3], 1) : 0;
    int b3 = v3 ? atomicAdd(&cur2[d3], 1) : 0;
    if (po0 < SLOT) padj[(size_t)s0 * SLOT + po0] = make_int2(d0, e0);
    if (a0 < SLOT2) adj2[(size_t)s0 * SLOT2 + a0] = d0;
    if (b0 < SLOT2) adj2[(size_t)d0 * SLOT2 + b0] = s0;
    if (v1 && po1 < SLOT) padj[(size_t)s1 * SLOT + po1] = make_int2(d1, e1);
    if (v1 && a1 < SLOT2) adj2[(size_t)s1 * SLOT2 + a1] = d1;
    if (v1 && b1 < SLOT2) adj2[(size_t)d1 * SLOT2 + b1] = s1;
    if (v2 && po2 < SLOT) padj[(size_t)s2 * SLOT + po2] = make_int2(d2, e2);
    if (v2 && a2 < SLOT2) adj2[(size_t)s2 * SLOT2 + a2] = d2;
    if (v2 && b2 < SLOT2) adj2[(size_t)d2 * SLOT2 + b2] = s2;
    if (v3 && po3 < SLOT) padj[(size_t)s3 * SLOT + po3] = make_int2(d3, e3);
    if (v3 && a3 < SLOT2) adj2[(size_t)s3 * SLOT2 + a3] = d3;
    if (v3 && b3 < SLOT2) adj2[(size_t)d3 * SLOT2 + b3] = s3;
}

// ---------------- scan of out-counts -> dense edata offsets --------------------
__global__ __launch_bounds__(256) void bsum_kernel(const int* __restrict__ deg,
                                                   int* __restrict__ bsum, int N) {
    __shared__ int sd[256];
    int i = blockIdx.x * 256 + threadIdx.x;
    sd[threadIdx.x] = (i < N) ? min(deg[i], SLOT) : 0;
    __syncthreads();
    for (int s = 128; s > 0; s >>= 1) {
        if (threadIdx.x < s) sd[threadIdx.x] += sd[threadIdx.x + s];
        __syncthreads();
    }
    if (threadIdx.x == 0) bsum[blockIdx.x] = sd[0];
}

__global__ __launch_bounds__(512) void scan_bsum_kernel(int* __restrict__ bsum, int NB) {
    __shared__ int s[512];
    int t = threadIdx.x;
    int v = (t < NB) ? bsum[t] : 0;
    s[t] = v;
    __syncthreads();
    for (int d = 1; d < 512; d <<= 1) {
        int add = (t >= d) ? s[t - d] : 0;
        __syncthreads();
        s[t] += add;
        __syncthreads();
    }
    if (t < NB) bsum[t] = s[t] - v;
}

__global__ __launch_bounds__(256) void rowptr_kernel(const int* __restrict__ deg,
                                                     const int* __restrict__ boff,
                                                     int* __restrict__ rowptr, int N) {
    __shared__ int s[256];
    int i = blockIdx.x * 256 + threadIdx.x;
    int t = threadIdx.x;
    int v = (i < N) ? min(deg[i], SLOT) : 0;
    s[t] = v;
    __syncthreads();
    for (int d = 1; d < 256; d <<= 1) {
        int add = (t >= d) ? s[t - d] : 0;
        __syncthreads();
        s[t] += add;
        __syncthreads();
    }
    if (i < N) rowptr[i] = boff[blockIdx.x] + s[t] - v;
}

// ---------------- compact padded out-buckets -> dense src-sorted edata ---------
// edataA (16 B/edge): [h2(es0,es1), h2(es2,es3), h2(qobs,qmask), s-as-bits]
// edataB (8 B/edge):  (d, e)
__global__ void compact_kernel(const int2* __restrict__ padj, const int* __restrict__ cur_o,
                               const int* __restrict__ rowptr2,
                               const float* __restrict__ estat,
                               const float* __restrict__ qobs,
                               const int* __restrict__ qmask,
                               float4* __restrict__ edataA, int2* __restrict__ edataB,
                               int N) {
    int t = blockIdx.x * blockDim.x + threadIdx.x;
    int node = t >> 2, lk = t & 3;
    if (node >= N) return;
    int cnt = min(cur_o[node], SLOT);
    int base = rowptr2[node];
    for (int k = lk; k < cnt; k += 4) {
        int2 de = padj[(size_t)node * SLOT + k];
        int e = de.y, d = de.x;
        float4 es = *(const float4*)&estat[(size_t)e * 4];
        union { float4 f; __half2 h[4]; int i[4]; } w0;
        w0.h[0] = __floats2half2_rn(es.x, es.y);
        w0.h[1] = __floats2half2_rn(es.z, es.w);
        w0.h[2] = __floats2half2_rn(qobs[e], (float)qmask[e]);
        w0.i[3] = node;
        edataA[base + k] = w0.f;
        edataB[base + k] = make_int2(d, e);
    }
}

// ---------------- gather-mean over unified adjacency (fp16) --------------------
// 16 lanes per node, float4 (16B) row loads, int4 index loads, 8-deep unroll.
__global__ __launch_bounds__(256) void gather_h_kernel(
    const int* __restrict__ cur2, const int* __restrict__ adj2,
    const __half* __restrict__ xh, __half* __restrict__ aggh, int N) {
    int node = blockIdx.x * 16 + (threadIdx.x >> 4);
    if (node >= N) return;
    const int th = threadIdx.x & 15;
    const int tot = min(cur2[node], SLOT2);
    const int* __restrict__ al = adj2 + (size_t)node * SLOT2;
    float a[8];
#pragma unroll
    for (int q = 0; q < 8; ++q) a[q] = 0.f;
    union F4H { float4 f; __half2 h[4]; };
    int j = 0;
    for (; j + 7 < tot; j += 8) {
        int4 i0 = *(const int4*)&al[j];
        int4 i1 = *(const int4*)&al[j + 4];
        F4H u[8];
        u[0].f = *(const float4*)&xh[(size_t)i0.x * H + th * 8];
        u[1].f = *(const float4*)&xh[(size_t)i0.y * H + th * 8];
        u[2].f = *(const float4*)&xh[(size_t)i0.z * H + th * 8];
        u[3].f = *(const float4*)&xh[(size_t)i0.w * H + th * 8];
        u[4].f = *(const float4*)&xh[(size_t)i1.x * H + th * 8];
        u[5].f = *(const float4*)&xh[(size_t)i1.y * H + th * 8];
        u[6].f = *(const float4*)&xh[(size_t)i1.z * H + th * 8];
        u[7].f = *(const float4*)&xh[(size_t)i1.w * H + th * 8];
#pragma unroll
        for (int q = 0; q < 4; ++q) {
            float2 s0 = __half22float2(u[0].h[q]);
            float2 s1 = __half22float2(u[1].h[q]);
            float2 s2 = __half22float2(u[2].h[q]);
            float2 s3 = __half22float2(u[3].h[q]);
            float2 s4 = __half22float2(u[4].h[q]);
            float2 s5 = __half22float2(u[5].h[q]);
            float2 s6 = __half22float2(u[6].h[q]);
            float2 s7 = __half22float2(u[7].h[q]);
            a[2 * q]     += ((s0.x + s1.x) + (s2.x + s3.x)) + ((s4.x + s5.x) + (s6.x + s7.x));
            a[2 * q + 1] += ((s0.y + s1.y) + (s2.y + s3.y)) + ((s4.y + s5.y) + (s6.y + s7.y));
        }
    }
    for (; j + 3 < tot; j += 4) {
        int4 i0 = *(const int4*)&al[j];
        F4H u[4];
        u[0].f = *(const float4*)&xh[(size_t)i0.x * H + th * 8];
        u[1].f = *(const float4*)&xh[(size_t)i0.y * H + th * 8];
        u[2].f = *(const float4*)&xh[(size_t)i0.z * H + th * 8];
        u[3].f = *(const float4*)&xh[(size_t)i0.w * H + th * 8];
#pragma unroll
        for (int q = 0; q < 4; ++q) {
            float2 s0 = __half22float2(u[0].h[q]);
            float2 s1 = __half22float2(u[1].h[q]);
            float2 s2 = __half22float2(u[2].h[q]);
            float2 s3 = __half22float2(u[3].h[q]);
            a[2 * q]     += (s0.x + s1.x) + (s2.x + s3.x);
            a[2 * q + 1] += (s0.y + s1.y) + (s2.y + s3.y);
        }
    }
    for (; j < tot; ++j) {
        int n1 = al[j];
        F4H u1;
        u1.f = *(const float4*)&xh[(size_t)n1 * H + th * 8];
#pragma unroll
        for (int q = 0; q < 4; ++q) {
            float2 p = __half22float2(u1.h[q]);
            a[2 * q] += p.x;
            a[2 * q + 1] += p.y;
        }
    }
    float iv = 1.0f / fmaxf((float)tot, 1.0f);
    F4H o;
#pragma unroll
    for (int q = 0; q < 4; ++q)
        o.h[q] = __floats2half2_rn(a[2 * q] * iv, a[2 * q + 1] * iv);
    *(float4*)&aggh[(size_t)node * H + th * 8] = o.f;
}

// ---------------- unified weight repack + node encoder (one dispatch) ----------
__global__ void repack_all_kernel(
    const float* __restrict__ Wself, const float* __restrict__ Wneigh,
    unsigned short* __restrict__ WLh, unsigned short* __restrict__ WLl,
    const float* __restrict__ erW1, const float* __restrict__ erb1,
    const float* __restrict__ eaW1, const float* __restrict__ eab1,
    unsigned short* __restrict__ WEh, unsigned short* __restrict__ WEl,
    float* __restrict__ bias512,
    const float* __restrict__ nrW1, const float* __restrict__ naW1,
    const float* __restrict__ nrb1, const float* __restrict__ nab1,
    const float* __restrict__ nrW2, const float* __restrict__ naW2,
    unsigned short* __restrict__ WNh, unsigned short* __restrict__ WNl,
    float* __restrict__ bias_nd, float* __restrict__ w2_nd,
    const float* __restrict__ ns, const float* __restrict__ pobs,
    const int* __restrict__ pmask, const float* __restrict__ Wenc,
    const float* __restrict__ benc, __half* __restrict__ xh, int N) {
    int idx = blockIdx.x * 256 + threadIdx.x;
    if (idx < 98304) {
        int l = idx >> 15;
        int rem = idx & 32767;
        int k = rem >> 7, n = rem & 127;
        float v = (k < 128) ? Wself[l * 16384 + k * 128 + n]
                            : Wneigh[l * 16384 + (k - 128) * 128 + n];
        int chunk = k >> 5, j = k & 7, q = (k >> 3) & 3;
        int lane = q * 16 + (n & 15), jt = n >> 4;
        size_t dst = (size_t)l * 32768 + (((size_t)(chunk * 8 + jt) * 64 + lane) * 8 + j);
        unsigned short hi = f2h(v);
        WLh[dst] = hi;
        WLl[dst] = f2bf(v - h2f(hi));
    } else if (idx < 163840) {
        int i2 = idx - 98304;
        int k = i2 >> 9, n = i2 & 511;
        float v;
        if (n < 128)       v = erW1[k * 128 + n];
        else if (n < 256)  v = eaW1[k * 128 + (n - 128)];
        else if (n < 384)  v = erW1[(128 + k) * 128 + (n - 256)];
        else               v = eaW1[(128 + k) * 128 + (n - 384)];
        int chunk = k >> 5, j = k & 7, q = (k >> 3) & 3;
        int lane = q * 16 + (n & 15), jt = n >> 4;
        size_t dst = ((size_t)(chunk * 32 + jt) * 64 + lane) * 8 + j;
        unsigned short hi = f2h(v);
        WEh[dst] = hi;
        WEl[dst] = f2bf(v - h2f(hi));
        if (k == 0) {
            float b = 0.0f;
            if (n >= 256 && n < 384) b = erb1[n - 256];
            else if (n >= 384) b = eab1[n - 384];
            bias512[n] = b;
        }
    } else if (idx < 196608) {
        int i3 = idx - 163840;
        int k = i3 >> 8, n = i3 & 255;
        float v = (n < 128) ? nrW1[k * 128 + n] : naW1[k * 128 + (n - 128)];
        int chunk = k >> 5, j = k & 7, q = (k >> 3) & 3;
        int lane = q * 16 + (n & 15), jt = n >> 4;
        size_t dst = ((size_t)(chunk * 16 + jt) * 64 + lane) * 8 + j;
        unsigned short hi = f2h(v);
        WNh[dst] = hi;
        WNl[dst] = f2bf(v - h2f(hi));
        if (k == 0) {
            bias_nd[n] = (n < 128) ? nrb1[n] : nab1[n - 128];
            w2_nd[n] = (n < 128) ? nrW2[n] : naW2[n - 128];
        }
    } else {
        int i4 = idx - 196608;
        if (i4 < N * H) {
            int n = i4 >> 7, h = i4 & 127;
            float f[8];
#pragma unroll
            for (int j = 0; j < 6; j++) f[j] = ns[n * 6 + j];
            f[6] = pobs[n];
            f[7] = (float)pmask[n];
            float s = benc[h];
#pragma unroll
            for (int k = 0; k < 8; k++) s += f[k] * Wenc[k * H + h];
            xh[i4] = __float2half(s);
        }
    }
}

// ---------------- GraphSAGE layer GEMM: raw-f16 A, f16+bf16 2-term MFMA --------
__global__ __launch_bounds__(256) void layer_gemm_kernel(
    const __half* __restrict__ A0, const __half* __restrict__ A1,
    const unsigned short* __restrict__ Wh, const unsigned short* __restrict__ Wl,
    const float* __restrict__ bias, __half* __restrict__ outh,
    int N, int do_relu, int row_tiles) {
    const int tid = threadIdx.x;
    const int lane = tid & 63;
    const int rt = blockIdx.x * 4 + (tid >> 6);
    if (rt >= row_tiles) return;
    const int m = lane & 15, quad = lane >> 4;

    f32x4v acc[2][8];
#pragma unroll
    for (int mt = 0; mt < 2; ++mt)
#pragma unroll
        for (int jt = 0; jt < 8; ++jt) acc[mt][jt] = (f32x4v){0.f, 0.f, 0.f, 0.f};

#pragma unroll
    for (int ph = 0; ph < 2; ++ph) {
        const __half* __restrict__ Ap = (ph == 0) ? A0 : A1;
#pragma unroll
        for (int c = 0; c < 4; ++c) {
            s16x8 ar[2], ab[2];
#pragma unroll
            for (int mt = 0; mt < 2; ++mt) {
                int row = rt * 32 + mt * 16 + m;
                ar[mt] = (row < N) ? *(const s16x8*)&Ap[(size_t)row * H + c * 32 + quad * 8]
                                   : (s16x8){0, 0, 0, 0, 0, 0, 0, 0};
                ab[mt] = h8_to_bf8(ar[mt]);
            }
            const int cglob = ph * 4 + c;
#pragma unroll
            for (int jt = 0; jt < 8; ++jt) {
                const size_t fo = ((size_t)(cglob * 8 + jt) * 64 + lane) * 8;
                s16x8 bh = *(const s16x8*)&Wh[fo];
                s16x8 bl = *(const s16x8*)&Wl[fo];
#pragma unroll
                for (int mt = 0; mt < 2; ++mt) {
                    acc[mt][jt] = mfma_h(ar[mt], bh, acc[mt][jt]);
                    acc[mt][jt] = __builtin_amdgcn_mfma_f32_16x16x32_bf16(ab[mt], bl, acc[mt][jt], 0, 0, 0);
                }
            }
        }
    }
#pragma unroll
    for (int jt = 0; jt < 8; ++jt) {
        int col = jt * 16 + m;
        float b = bias[col];
#pragma unroll
        for (int mt = 0; mt < 2; ++mt) {
#pragma unroll
            for (int r = 0; r < 4; ++r) {
                int row = rt * 32 + mt * 16 + quad * 4 + r;
                if (row < N) {
                    float v = acc[mt][jt][r] + b;
                    if (do_relu) v = fmaxf(v, 0.f);
                    outh[(size_t)row * H + col] = __float2half(v);
                }
            }
        }
    }
}

// ---------------- node heads: raw-f16 A, fused W2 reduction --------------------
__global__ __launch_bounds__(256) void node_head_mfma_kernel(
    const __half* __restrict__ x,
    const unsigned short* __restrict__ Wh, const unsigned short* __restrict__ Wl,
    const float* __restrict__ bias256, const float* __restrict__ w2vec,
    const float* __restrict__ b2r, const float* __restrict__ b2a,
    float* __restrict__ out_p, float* __restrict__ out_nl, int N, int row_tiles) {
    const int tid = threadIdx.x;
    const int lane = tid & 63;
    const int wid = blockIdx.x * 4 + (tid >> 6);
    if (wid >= row_tiles) return;
    const int m = lane & 15, quad = lane >> 4;
    const int row0 = wid * 16;

    f32x4v acc[16];
#pragma unroll
    for (int jt = 0; jt < 16; ++jt) acc[jt] = (f32x4v){0.f, 0.f, 0.f, 0.f};

#pragma unroll
    for (int c = 0; c < 4; ++c) {
        int row = row0 + m;
        s16x8 ar = (row < N) ? *(const s16x8*)&x[(size_t)row * H + c * 32 + quad * 8]
                             : (s16x8){0, 0, 0, 0, 0, 0, 0, 0};
        s16x8 ab = h8_to_bf8(ar);
#pragma unroll
        for (int jt = 0; jt < 16; ++jt) {
            const size_t fo = ((size_t)(c * 16 + jt) * 64 + lane) * 8;
            s16x8 bh = *(const s16x8*)&Wh[fo];
            s16x8 bl = *(const s16x8*)&Wl[fo];
            acc[jt] = mfma_h(ar, bh, acc[jt]);
            acc[jt] = __builtin_amdgcn_mfma_f32_16x16x32_bf16(ab, bl, acc[jt], 0, 0, 0);
        }
    }
    float sr[4] = {0.f, 0.f, 0.f, 0.f}, sa[4] = {0.f, 0.f, 0.f, 0.f};
#pragma unroll
    for (int jt = 0; jt < 16; ++jt) {
        int col = jt * 16 + m;
        float b1 = bias256[col];
        float w2 = w2vec[col];
#pragma unroll
        for (int r = 0; r < 4; ++r) {
            float h = fmaxf(acc[jt][r] + b1, 0.f) * w2;
            if (jt < 8) sr[r] += h; else sa[r] += h;
        }
    }
#pragma unroll
    for (int r = 0; r < 4; ++r) {
#pragma unroll
        for (int off = 1; off < 16; off <<= 1) {
            sr[r] += __shfl_xor(sr[r], off);
            sa[r] += __shfl_xor(sa[r], off);
        }
    }
    if (m == 0) {
        float br = b2r[0], ba = b2a[0];
#pragma unroll
        for (int r = 0; r < 4; ++r) {
            int row = row0 + quad * 4 + r;
            if (row < N) {
                out_p[row] = sr[r] + br;
                out_nl[row] = sa[r] + ba;
            }
        }
    }
}

// ---------------- edge-head GEMM: LDS A tile (f16 + bf16 planes) ---------------
__global__ __launch_bounds__(256) void edge_gemm_kernel(
    const __half* __restrict__ xh,
    const unsigned short* __restrict__ Wh, const unsigned short* __restrict__ Wl,
    const float* __restrict__ bias512, __half* __restrict__ P, int N) {
    __shared__ unsigned short sMem[2][64][136];   // [0]=raw f16 A, [1]=bf16(A); later overlaid with C tile
    const int rt = blockIdx.x >> 1, ch = blockIdx.x & 1;
    const int tid = threadIdx.x;
    {
        int row = tid >> 2;
        int k0 = (tid & 3) * 32;
        int gr = rt * 64 + row;
#pragma unroll
        for (int i = 0; i < 4; ++i) {
            int k = k0 + i * 8;
            s16x8 raw = (gr < N) ? *(const s16x8*)&xh[(size_t)gr * H + k]
                                 : (s16x8){0, 0, 0, 0, 0, 0, 0, 0};
            *(s16x8*)&sMem[0][row][k] = raw;
            *(s16x8*)&sMem[1][row][k] = h8_to_bf8(raw);
        }
    }
    __syncthreads();
    const int lane = tid & 63, w = tid >> 6;
    const int m = lane & 15, quad = lane >> 4;

    f32x4v acc[4][4];
#pragma unroll
    for (int mt = 0; mt < 4; ++mt)
#pragma unroll
        for (int jt = 0; jt < 4; ++jt) acc[mt][jt] = (f32x4v){0.f, 0.f, 0.f, 0.f};

#pragma unroll
    for (int c = 0; c < 4; ++c) {
        s16x8 ah[4], ab[4];
#pragma unroll
        for (int mt = 0; mt < 4; ++mt) {
            ah[mt] = *(const s16x8*)&sMem[0][mt * 16 + m][c * 32 + quad * 8];
            ab[mt] = *(const s16x8*)&sMem[1][mt * 16 + m][c * 32 + quad * 8];
        }
#pragma unroll
        for (int jt = 0; jt < 4; ++jt) {
            const int jts = ch * 16 + w * 4 + jt;
            const size_t fo = ((size_t)(c * 32 + jts) * 64 + lane) * 8;
            s16x8 bh = *(const s16x8*)&Wh[fo];
            s16x8 bl = *(const s16x8*)&Wl[fo];
#pragma unroll
            for (int mt = 0; mt < 4; ++mt) {
                acc[mt][jt] = mfma_h(ah[mt], bh, acc[mt][jt]);
                acc[mt][jt] = __builtin_amdgcn_mfma_f32_16x16x32_bf16(ab[mt], bl, acc[mt][jt], 0, 0, 0);
            }
        }
    }
    __syncthreads();   // all A reads complete before overlay
    __half* stage = (__half*)sMem;   // 34816 B >= 32768 B
#pragma unroll
    for (int jt = 0; jt < 4; ++jt) {
        int col = (w * 4 + jt) * 16 + m;   // local col 0..255
        float b = bias512[ch * 256 + col];
#pragma unroll
        for (int mt = 0; mt < 4; ++mt) {
#pragma unroll
            for (int r = 0; r < 4; ++r) {
                int rowl = mt * 16 + quad * 4 + r;
                stage[rowl * 256 + col] = __float2half(acc[mt][jt][r] + b);
            }
        }
    }
    __syncthreads();
#pragma unroll
    for (int it = 0; it < 8; ++it) {
        int idx = it * 256 + tid;          // 0..2047, each = 8 halves
        int rowl = idx >> 5;
        int colh = (idx & 31) * 8;
        int gr = rt * 64 + rowl;
        if (gr < N) {
            *(float4*)&P[(size_t)gr * 512 + ch * 256 + colh] =
                *(const float4*)&stage[rowl * 256 + colh];
        }
    }
}

// ---------------- fused edge epilogue: packed-fp16 hot loop --------------------
__global__ __launch_bounds__(256) void edge_out_fused3_kernel(
    const __half* __restrict__ P, const float4* __restrict__ edataA,
    const int2* __restrict__ edataB,
    const float* __restrict__ erW1, const float* __restrict__ erW2,
    const float* __restrict__ erb2,
    const float* __restrict__ eaW1, const float* __restrict__ eaW2,
    const float* __restrict__ eab2,
    float* __restrict__ out_q, float* __restrict__ out_el, int E) {
    const int lane = threadIdx.x & 63;
    const int half = lane >> 5, th = lane & 31;
    const int head = th >> 4;
    const int d0 = (th & 15) * 8;
    const long hw = ((long)blockIdx.x * 4 + (threadIdx.x >> 6)) * 2 + half;

    const float* W1 = head ? eaW1 : erW1;
    const float* W2 = head ? eaW2 : erW2;
    __half2 wch[6][4];
#pragma unroll
    for (int j = 0; j < 6; j++) {
        float4 t0 = *(const float4*)&W1[(256 + j) * H + d0];
        float4 t1 = *(const float4*)&W1[(256 + j) * H + d0 + 4];
        wch[j][0] = __floats2half2_rn(t0.x, t0.y);
        wch[j][1] = __floats2half2_rn(t0.z, t0.w);
        wch[j][2] = __floats2half2_rn(t1.x, t1.y);
        wch[j][3] = __floats2half2_rn(t1.z, t1.w);
    }
    __half2 w2h[4];
    {
        float4 t0 = *(const float4*)&W2[d0];
        float4 t1 = *(const float4*)&W2[d0 + 4];
        w2h[0] = __floats2half2_rn(t0.x, t0.y);
        w2h[1] = __floats2half2_rn(t0.z, t0.w);
        w2h[2] = __floats2half2_rn(t1.x, t1.y);
        w2h[3] = __floats2half2_rn(t1.z, t1.w);
    }
    const float b2 = head ? eab2[0] : erb2[0];

    union F4H { float4 f; __half2 h[4]; };
    const long j0 = hw * 4;
#pragma unroll
    for (int it = 0; it < 4; ++it) {
        long jj = j0 + it;
        if (jj < E) {
            F4H r0;
            r0.f = edataA[jj];
            int2 de = edataB[jj];
            int s = __float_as_int(r0.f.w);
            int d = de.x;
            int e = de.y;
            __half2 esx = __low2half2(r0.h[0]);
            __half2 esy = __high2half2(r0.h[0]);
            __half2 esz = __low2half2(r0.h[1]);
            __half2 esw = __high2half2(r0.h[1]);
            __half2 qoh = __low2half2(r0.h[2]);
            __half2 qmh = __high2half2(r0.h[2]);
            F4H sv, dv;
            sv.f = *(const float4*)&P[(size_t)s * 512 + th * 8];
            dv.f = *(const float4*)&P[(size_t)d * 512 + 256 + th * 8];
            float part = 0.f;
#pragma unroll
            for (int q = 0; q < 4; ++q) {
                __half2 hid = sv.h[q] + dv.h[q];
                hid = __hfma2(esx, wch[0][q], hid);
                hid = __hfma2(esy, wch[1][q], hid);
                hid = __hfma2(esz, wch[2][q], hid);
                hid = __hfma2(esw, wch[3][q], hid);
                hid = __hfma2(qoh, wch[4][q], hid);
                hid = __hfma2(qmh, wch[5][q], hid);
                hid = relu2(hid);
                part = fdot2f(hid, w2h[q], part);
            }
#pragma unroll
            for (int off = 1; off < 16; off <<= 1) part += __shfl_xor(part, off);
            if ((th & 15) == 0) {
                if (head == 0) out_q[e] = part + b2;
                else out_el[e] = part + b2;
            }
        }
    }
}

// ------------------------------------------------------------------------------
extern "C" void kernel_launch(void* const* d_in, const int* in_sizes, int n_in,
                              void* d_out, int out_size, void* d_ws, size_t ws_size,
                              hipStream_t stream) {
    const int* eidx = (const int*)d_in[0];
    const float* node_static = (const float*)d_in[1];
    const float* edge_static = (const float*)d_in[2];
    const float* p_obs = (const float*)d_in[3];
    const float* q_obs = (const float*)d_in[4];
    const int* p_mask = (const int*)d_in[5];
    const int* q_mask = (const int*)d_in[6];
    const float* W_enc = (const float*)d_in[7];
    const float* b_enc = (const float*)d_in[8];
    const float* W_self = (const float*)d_in[9];
    const float* W_neigh = (const float*)d_in[10];
    const float* b_gnn = (const float*)d_in[11];
    const float* nrW1 = (const float*)d_in[12]; const float* nrb1 = (const float*)d_in[13];
    const float* nrW2 = (const float*)d_in[14]; const float* nrb2 = (const float*)d_in[15];
    const float* naW1 = (const float*)d_in[16]; const float* nab1 = (const float*)d_in[17];
    const float* naW2 = (const float*)d_in[18]; const float* nab2 = (const float*)d_in[19];
    const float* erW1 = (const float*)d_in[20]; const float* erb1 = (const float*)d_in[21];
    const float* erW2 = (const float*)d_in[22]; const float* erb2 = (const float*)d_in[23];
    const float* eaW1 = (const float*)d_in[24]; const float* eab1 = (const float*)d_in[25];
    const float* eaW2 = (const float*)d_in[26]; const float* eab2 = (const float*)d_in[27];

    const int E = in_sizes[0] / 2;
    const int N = in_sizes[3];
    const int* src = eidx;
    const int* dst = eidx + E;

    float* out = (float*)d_out;
    float* p_hat = out;
    float* q_hat = out + N;
    float* node_logits = out + N + E;
    float* edge_logits = out + 2 * N + E;

    __half* xh0 = (__half*)d_ws;               // [N,128] f16
    __half* xh1 = xh0 + (size_t)N * H;         // [N,128] f16
    __half* P = xh1 + (size_t)N * H;           // [N,512] f16
    float4* edataA = (float4*)(P + (size_t)N * 512);   // E x 16 B
    int2* edataB = (int2*)(edataA + (size_t)E);        // E x 8 B
    int2* padj = (int2*)(edataB + (size_t)E);          // [N,SLOT] (dst, e)
    int* adj2 = (int*)(padj + (size_t)N * SLOT);       // [N,SLOT2] unified neighbors
    int* cur_o = adj2 + (size_t)N * SLOT2;     // N
    int* cur2 = cur_o + N;                     // N
    int* rowptr2 = cur2 + N;                   // N
    int* bsum = rowptr2 + N;                   // 512
    unsigned short* WLh = (unsigned short*)(bsum + 512);   // 3*32768
    unsigned short* WLl = WLh + 3 * 32768;
    unsigned short* WEh = WLl + 3 * 32768;     // 65536
    unsigned short* WEl = WEh + 65536;
    unsigned short* WNh = WEl + 65536;         // 32768
    unsigned short* WNl = WNh + 32768;
    float* bias512 = (float*)(WNl + 32768);    // 512
    float* bias_nd = bias512 + 512;            // 256
    float* w2_nd = bias_nd + 256;              // 256

    const int NB = (N + 255) / 256;
    const int RT32 = (N + 31) / 32;
    const int RT16 = (N + 15) / 16;
    const int RT64 = (N + 63) / 64;

    hipMemsetAsync(cur_o, 0, (size_t)2 * N * sizeof(int), stream);
    repack_all_kernel<<<768 + (N * H + 255) / 256, 256, 0, stream>>>(
        W_self, W_neigh, WLh, WLl,
        erW1, erb1, eaW1, eab1, WEh, WEl, bias512,
        nrW1, naW1, nrb1, nab1, nrW2, naW2, WNh, WNl, bias_nd, w2_nd,
        node_static, p_obs, p_mask, W_enc, b_enc, xh0, N);
    const int quarter = (E + 3) / 4;
    fill_pad_kernel<<<(quarter + 255) / 256, 256, 0, stream>>>(src, dst, cur_o, cur2,
                                                               padj, adj2, E, quarter);
    bsum_kernel<<<NB, 256, 0, stream>>>(cur_o, bsum, N);
    scan_bsum_kernel<<<1, 512, 0, stream>>>(bsum, NB);
    rowptr_kernel<<<NB, 256, 0, stream>>>(cur_o, bsum, rowptr2, N);
    compact_kernel<<<(4 * N + 255) / 256, 256, 0, stream>>>(
        padj, cur_o, rowptr2, edge_static, q_obs, q_mask, edataA, edataB, N);

    __half* cur = xh0;
    __half* other = xh1;
    for (int l = 0; l < 3; ++l) {
        gather_h_kernel<<<(N + 15) / 16, 256, 0, stream>>>(cur2, adj2, cur, other, N);
        layer_gemm_kernel<<<(RT32 + 3) / 4, 256, 0, stream>>>(
            cur, other, WLh + (size_t)l * 32768, WLl + (size_t)l * 32768,
            b_gnn + l * H, other, N, (l < 2) ? 1 : 0, RT32);
        __half* t = cur; cur = other; other = t;
    }

    node_head_mfma_kernel<<<(RT16 + 3) / 4, 256, 0, stream>>>(
        cur, WNh, WNl, bias_nd, w2_nd, nrb2, nab2, p_hat, node_logits, N, RT16);

    edge_gemm_kernel<<<RT64 * 2, 256, 0, stream>>>(cur, WEh, WEl, bias512, P, N);
    edge_out_fused3_kernel<<<(E + 31) / 32, 256, 0, stream>>>(
        P, edataA, edataB, erW1, erW2, erb2, eaW1, eaW2, eab2, q_hat, edge_logits, E);
}

// Round 6
// 738.776 us; speedup vs baseline: 1.0556x; 1.0556x over previous
//
#include <hip/hip_runtime.h>
#include <hip/hip_bf16.h>
#include <hip/hip_fp16.h>

#define H 128
#define SLOT 32   // per-node, per-direction adjacency capacity (deg ~ Poisson(6); P(>=32) ~ 7e-14)

typedef short s16x8 __attribute__((ext_vector_type(8)));
typedef _Float16 h16x8 __attribute__((ext_vector_type(8)));
typedef float f32x4v __attribute__((ext_vector_type(4)));

__device__ __forceinline__ unsigned short f2bf(float v) {
    __hip_bfloat16 h = __float2bfloat16(v);
    return *reinterpret_cast<unsigned short*>(&h);
}
__device__ __forceinline__ float bf2f(unsigned short u) {
    unsigned int x = ((unsigned int)u) << 16;
    return *reinterpret_cast<float*>(&x);
}
__device__ __forceinline__ unsigned short f2h(float v) {
    __half h = __float2half(v);
    return *reinterpret_cast<unsigned short*>(&h);
}
__device__ __forceinline__ float h2f(unsigned short u) {
    __half h = *reinterpret_cast<__half*>(&u);
    return __half2float(h);
}

// convert 8 packed f16 -> 8 packed bf16 (truncating re-round; used for the lo-plane MFMA)
__device__ __forceinline__ s16x8 h8_to_bf8(s16x8 a) {
    union { s16x8 v; __half2 h[4]; } u; u.v = a;
    union { s16x8 v; unsigned short u[8]; } r;
#pragma unroll
    for (int q = 0; q < 4; ++q) {
        float2 t = __half22float2(u.h[q]);
        r.u[2 * q] = f2bf(t.x);
        r.u[2 * q + 1] = f2bf(t.y);
    }
    return r.v;
}

// f16 MFMA wrapper (bit-cast short8 -> half8)
__device__ __forceinline__ f32x4v mfma_h(s16x8 a, s16x8 b, f32x4v c) {
    h16x8 ha = __builtin_bit_cast(h16x8, a);
    h16x8 hb = __builtin_bit_cast(h16x8, b);
    return __builtin_amdgcn_mfma_f32_16x16x32_f16(ha, hb, c, 0, 0, 0);
}

// packed-fp16 relu: single VOP3P v_pk_max_f16 against +0 (inline const 0)
__device__ __forceinline__ __half2 relu2(__half2 v) {
    unsigned int u = *reinterpret_cast<unsigned int*>(&v);
    unsigned int r;
    asm("v_pk_max_f16 %0, %1, 0" : "=v"(r) : "v"(u));
    return *reinterpret_cast<__half2*>(&r);
}

// packed-fp16 dot2 accumulate into f32: d = a.x*b.x + a.y*b.y + c
__device__ __forceinline__ float fdot2f(__half2 a, __half2 b, float c) {
    unsigned int ua = *reinterpret_cast<unsigned int*>(&a);
    unsigned int ub = *reinterpret_cast<unsigned int*>(&b);
    float r;
    asm("v_dot2_f32_f16 %0, %1, %2, %3" : "=v"(r) : "v"(ua), "v"(ub), "v"(c));
    return r;
}

// ---------------- mega pre-pass: fill_pad + weight repack + node encoder -------
// Independent work co-dispatched in one kernel. fill_pad blocks FIRST (they are
// scatter-latency-bound at ~19% occupancy and the longest pole); repack + enc
// stream in behind them and overlap. Dependencies (bsum reads cur_o) are across
// kernel boundaries only.
__global__ void pre_kernel(
    // fill_pad part
    const int* __restrict__ src, const int* __restrict__ dst,
    int* __restrict__ cur_o, int* __restrict__ cur_i,
    int2* __restrict__ padj, int* __restrict__ adj_in, int E, int quarter, int FB,
    // repack part
    const float* __restrict__ Wself, const float* __restrict__ Wneigh,
    unsigned short* __restrict__ WLh, unsigned short* __restrict__ WLl,
    const float* __restrict__ erW1, const float* __restrict__ erb1,
    const float* __restrict__ eaW1, const float* __restrict__ eab1,
    unsigned short* __restrict__ WEh, unsigned short* __restrict__ WEl,
    float* __restrict__ bias512,
    const float* __restrict__ nrW1, const float* __restrict__ naW1,
    const float* __restrict__ nrb1, const float* __restrict__ nab1,
    const float* __restrict__ nrW2, const float* __restrict__ naW2,
    unsigned short* __restrict__ WNh, unsigned short* __restrict__ WNl,
    float* __restrict__ bias_nd, float* __restrict__ w2_nd,
    // enc part
    const float* __restrict__ ns, const float* __restrict__ pobs,
    const int* __restrict__ pmask, const float* __restrict__ Wenc,
    const float* __restrict__ benc, __half* __restrict__ xh, int N) {
    const int b = blockIdx.x;
    if (b < FB) {
        int t = b * 256 + threadIdx.x;
        if (t >= quarter) return;
        int e0 = t, e1 = t + quarter, e2 = t + 2 * quarter, e3 = t + 3 * quarter;
        bool v1 = e1 < E, v2 = e2 < E, v3 = e3 < E;
        int s0 = src[e0], d0 = dst[e0];
        int s1 = v1 ? src[e1] : 0, d1 = v1 ? dst[e1] : 0;
        int s2 = v2 ? src[e2] : 0, d2 = v2 ? dst[e2] : 0;
        int s3 = v3 ? src[e3] : 0, d3 = v3 ? dst[e3] : 0;
        int po0 = atomicAdd(&cur_o[s0], 1);
        int pi0 = atomicAdd(&cur_i[d0], 1);
        int po1 = v1 ? atomicAdd(&cur_o[s1], 1) : 0;
        int pi1 = v1 ? atomicAdd(&cur_i[d1], 1) : 0;
        int po2 = v2 ? atomicAdd(&cur_o[s2], 1) : 0;
        int pi2 = v2 ? atomicAdd(&cur_i[d2], 1) : 0;
        int po3 = v3 ? atomicAdd(&cur_o[s3], 1) : 0;
        int pi3 = v3 ? atomicAdd(&cur_i[d3], 1) : 0;
        if (po0 < SLOT) padj[(size_t)s0 * SLOT + po0] = make_int2(d0, e0);
        if (pi0 < SLOT) adj_in[(size_t)d0 * SLOT + pi0] = s0;
        if (v1 && po1 < SLOT) padj[(size_t)s1 * SLOT + po1] = make_int2(d1, e1);
        if (v1 && pi1 < SLOT) adj_in[(size_t)d1 * SLOT + pi1] = s1;
        if (v2 && po2 < SLOT) padj[(size_t)s2 * SLOT + po2] = make_int2(d2, e2);
        if (v2 && pi2 < SLOT) adj_in[(size_t)d2 * SLOT + pi2] = s2;
        if (v3 && po3 < SLOT) padj[(size_t)s3 * SLOT + po3] = make_int2(d3, e3);
        if (v3 && pi3 < SLOT) adj_in[(size_t)d3 * SLOT + pi3] = s3;
        return;
    }
    int idx = (b - FB) * 256 + threadIdx.x;
    if (idx < 98304) {
        int l = idx >> 15;
        int rem = idx & 32767;
        int k = rem >> 7, n = rem & 127;
        float v = (k < 128) ? Wself[l * 16384 + k * 128 + n]
                            : Wneigh[l * 16384 + (k - 128) * 128 + n];
        int chunk = k >> 5, j = k & 7, q = (k >> 3) & 3;
        int lane = q * 16 + (n & 15), jt = n >> 4;
        size_t dstp = (size_t)l * 32768 + (((size_t)(chunk * 8 + jt) * 64 + lane) * 8 + j);
        unsigned short hi = f2h(v);
        WLh[dstp] = hi;
        WLl[dstp] = f2bf(v - h2f(hi));
    } else if (idx < 163840) {
        int i2 = idx - 98304;
        int k = i2 >> 9, n = i2 & 511;
        float v;
        if (n < 128)       v = erW1[k * 128 + n];
        else if (n < 256)  v = eaW1[k * 128 + (n - 128)];
        else if (n < 384)  v = erW1[(128 + k) * 128 + (n - 256)];
        else               v = eaW1[(128 + k) * 128 + (n - 384)];
        int chunk = k >> 5, j = k & 7, q = (k >> 3) & 3;
        int lane = q * 16 + (n & 15), jt = n >> 4;
        size_t dstp = ((size_t)(chunk * 32 + jt) * 64 + lane) * 8 + j;
        unsigned short hi = f2h(v);
        WEh[dstp] = hi;
        WEl[dstp] = f2bf(v - h2f(hi));
        if (k == 0) {
            float bb = 0.0f;
            if (n >= 256 && n < 384) bb = erb1[n - 256];
            else if (n >= 384) bb = eab1[n - 384];
            bias512[n] = bb;
        }
    } else if (idx < 196608) {
        int i3 = idx - 163840;
        int k = i3 >> 8, n = i3 & 255;
        float v = (n < 128) ? nrW1[k * 128 + n] : naW1[k * 128 + (n - 128)];
        int chunk = k >> 5, j = k & 7, q = (k >> 3) & 3;
        int lane = q * 16 + (n & 15), jt = n >> 4;
        size_t dstp = ((size_t)(chunk * 16 + jt) * 64 + lane) * 8 + j;
        unsigned short hi = f2h(v);
        WNh[dstp] = hi;
        WNl[dstp] = f2bf(v - h2f(hi));
        if (k == 0) {
            bias_nd[n] = (n < 128) ? nrb1[n] : nab1[n - 128];
            w2_nd[n] = (n < 128) ? nrW2[n] : naW2[n - 128];
        }
    } else {
        int i4 = idx - 196608;
        if (i4 < N * H) {
            int n = i4 >> 7, h = i4 & 127;
            float f[8];
#pragma unroll
            for (int j = 0; j < 6; j++) f[j] = ns[n * 6 + j];
            f[6] = pobs[n];
            f[7] = (float)pmask[n];
            float s = benc[h];
#pragma unroll
            for (int k = 0; k < 8; k++) s += f[k] * Wenc[k * H + h];
            xh[i4] = __float2half(s);
        }
    }
}

// ---------------- scan of out-counts -> dense edata offsets --------------------
__global__ __launch_bounds__(256) void bsum_kernel(const int* __restrict__ deg,
                                                   int* __restrict__ bsum, int N) {
    __shared__ int sd[256];
    int i = blockIdx.x * 256 + threadIdx.x;
    sd[threadIdx.x] = (i < N) ? min(deg[i], SLOT) : 0;
    __syncthreads();
    for (int s = 128; s > 0; s >>= 1) {
        if (threadIdx.x < s) sd[threadIdx.x] += sd[threadIdx.x + s];
        __syncthreads();
    }
    if (threadIdx.x == 0) bsum[blockIdx.x] = sd[0];
}

__global__ __launch_bounds__(512) void scan_bsum_kernel(int* __restrict__ bsum, int NB) {
    __shared__ int s[512];
    int t = threadIdx.x;
    int v = (t < NB) ? bsum[t] : 0;
    s[t] = v;
    __syncthreads();
    for (int d = 1; d < 512; d <<= 1) {
        int add = (t >= d) ? s[t - d] : 0;
        __syncthreads();
        s[t] += add;
        __syncthreads();
    }
    if (t < NB) bsum[t] = s[t] - v;
}

__global__ __launch_bounds__(256) void rowptr_kernel(const int* __restrict__ deg,
                                                     const int* __restrict__ boff,
                                                     int* __restrict__ rowptr, int N) {
    __shared__ int s[256];
    int i = blockIdx.x * 256 + threadIdx.x;
    int t = threadIdx.x;
    int v = (i < N) ? min(deg[i], SLOT) : 0;
    s[t] = v;
    __syncthreads();
    for (int d = 1; d < 256; d <<= 1) {
        int add = (t >= d) ? s[t - d] : 0;
        __syncthreads();
        s[t] += add;
        __syncthreads();
    }
    if (i < N) rowptr[i] = boff[blockIdx.x] + s[t] - v;
}

// ---------------- compact padded out-buckets -> dense src-sorted edata ---------
// edataA (16 B/edge): [h2(es0,es1), h2(es2,es3), h2(qobs,qmask), s-as-bits]
// edataB (8 B/edge):  (d, e)
__global__ void compact_kernel(const int2* __restrict__ padj, const int* __restrict__ cur_o,
                               const int* __restrict__ rowptr2,
                               const float* __restrict__ estat,
                               const float* __restrict__ qobs,
                               const int* __restrict__ qmask,
                               float4* __restrict__ edataA, int2* __restrict__ edataB,
                               int N) {
    int t = blockIdx.x * blockDim.x + threadIdx.x;
    int node = t >> 2, lk = t & 3;
    if (node >= N) return;
    int cnt = min(cur_o[node], SLOT);
    int base = rowptr2[node];
    for (int k = lk; k < cnt; k += 4) {
        int2 de = padj[(size_t)node * SLOT + k];
        int e = de.y, d = de.x;
        float4 es = *(const float4*)&estat[(size_t)e * 4];
        union { float4 f; __half2 h[4]; int i[4]; } w0;
        w0.h[0] = __floats2half2_rn(es.x, es.y);
        w0.h[1] = __floats2half2_rn(es.z, es.w);
        w0.h[2] = __floats2half2_rn(qobs[e], (float)qmask[e]);
        w0.i[3] = node;
        edataA[base + k] = w0.f;
        edataB[base + k] = make_int2(d, e);
    }
}

// ---------------- gather-mean, unified out+in virtual list (fp16) --------------
// 16 lanes per node, float4 (16B) row loads, 4-deep unroll. At the random-access
// bandwidth floor (coalesced 256B rows); select overhead is hidden by latency.
__global__ __launch_bounds__(256) void gather_h_kernel(
    const int* __restrict__ cur_o, const int* __restrict__ cur_i,
    const int2* __restrict__ padj, const int* __restrict__ adj_in,
    const __half* __restrict__ xh, __half* __restrict__ aggh, int N) {
    int node = blockIdx.x * 16 + (threadIdx.x >> 4);
    if (node >= N) return;
    const int th = threadIdx.x & 15;
    const int co = min(cur_o[node], SLOT);
    const int ci = min(cur_i[node], SLOT);
    const int tot = co + ci;
    float a[8];
#pragma unroll
    for (int q = 0; q < 8; ++q) a[q] = 0.f;
    union F4H { float4 f; __half2 h[4]; };
    const int2* po = padj + (size_t)node * SLOT;
    const int* pi = adj_in + (size_t)node * SLOT;
    int j = 0;
    for (; j + 3 < tot; j += 4) {
        int n1 = (j < co) ? po[j].x : pi[j - co];
        int n2 = (j + 1 < co) ? po[j + 1].x : pi[j + 1 - co];
        int n3 = (j + 2 < co) ? po[j + 2].x : pi[j + 2 - co];
        int n4 = (j + 3 < co) ? po[j + 3].x : pi[j + 3 - co];
        F4H u1, u2, u3, u4;
        u1.f = *(const float4*)&xh[(size_t)n1 * H + th * 8];
        u2.f = *(const float4*)&xh[(size_t)n2 * H + th * 8];
        u3.f = *(const float4*)&xh[(size_t)n3 * H + th * 8];
        u4.f = *(const float4*)&xh[(size_t)n4 * H + th * 8];
#pragma unroll
        for (int q = 0; q < 4; ++q) {
            float2 p = __half22float2(u1.h[q]);
            float2 r = __half22float2(u2.h[q]);
            float2 s = __half22float2(u3.h[q]);
            float2 t = __half22float2(u4.h[q]);
            a[2 * q]     += (p.x + r.x) + (s.x + t.x);
            a[2 * q + 1] += (p.y + r.y) + (s.y + t.y);
        }
    }
    for (; j < tot; ++j) {
        int n1 = (j < co) ? po[j].x : pi[j - co];
        F4H u1;
        u1.f = *(const float4*)&xh[(size_t)n1 * H + th * 8];
#pragma unroll
        for (int q = 0; q < 4; ++q) {
            float2 p = __half22float2(u1.h[q]);
            a[2 * q] += p.x;
            a[2 * q + 1] += p.y;
        }
    }
    float iv = 1.0f / fmaxf((float)tot, 1.0f);
    F4H o;
#pragma unroll
    for (int q = 0; q < 4; ++q)
        o.h[q] = __floats2half2_rn(a[2 * q] * iv, a[2 * q + 1] * iv);
    *(float4*)&aggh[(size_t)node * H + th * 8] = o.f;
}

// ---------------- GraphSAGE layer GEMM: raw-f16 A, f16+bf16 2-term MFMA --------
__global__ __launch_bounds__(256) void layer_gemm_kernel(
    const __half* __restrict__ A0, const __half* __restrict__ A1,
    const unsigned short* __restrict__ Wh, const unsigned short* __restrict__ Wl,
    const float* __restrict__ bias, __half* __restrict__ outh,
    int N, int do_relu, int row_tiles) {
    const int tid = threadIdx.x;
    const int lane = tid & 63;
    const int rt = blockIdx.x * 4 + (tid >> 6);
    if (rt >= row_tiles) return;
    const int m = lane & 15, quad = lane >> 4;

    f32x4v acc[2][8];
#pragma unroll
    for (int mt = 0; mt < 2; ++mt)
#pragma unroll
        for (int jt = 0; jt < 8; ++jt) acc[mt][jt] = (f32x4v){0.f, 0.f, 0.f, 0.f};

#pragma unroll
    for (int ph = 0; ph < 2; ++ph) {
        const __half* __restrict__ Ap = (ph == 0) ? A0 : A1;
#pragma unroll
        for (int c = 0; c < 4; ++c) {
            s16x8 ar[2], ab[2];
#pragma unroll
            for (int mt = 0; mt < 2; ++mt) {
                int row = rt * 32 + mt * 16 + m;
                ar[mt] = (row < N) ? *(const s16x8*)&Ap[(size_t)row * H + c * 32 + quad * 8]
                                   : (s16x8){0, 0, 0, 0, 0, 0, 0, 0};
                ab[mt] = h8_to_bf8(ar[mt]);
            }
            const int cglob = ph * 4 + c;
#pragma unroll
            for (int jt = 0; jt < 8; ++jt) {
                const size_t fo = ((size_t)(cglob * 8 + jt) * 64 + lane) * 8;
                s16x8 bh = *(const s16x8*)&Wh[fo];
                s16x8 bl = *(const s16x8*)&Wl[fo];
#pragma unroll
                for (int mt = 0; mt < 2; ++mt) {
                    acc[mt][jt] = mfma_h(ar[mt], bh, acc[mt][jt]);
                    acc[mt][jt] = __builtin_amdgcn_mfma_f32_16x16x32_bf16(ab[mt], bl, acc[mt][jt], 0, 0, 0);
                }
            }
        }
    }
#pragma unroll
    for (int jt = 0; jt < 8; ++jt) {
        int col = jt * 16 + m;
        float b = bias[col];
#pragma unroll
        for (int mt = 0; mt < 2; ++mt) {
#pragma unroll
            for (int r = 0; r < 4; ++r) {
                int row = rt * 32 + mt * 16 + quad * 4 + r;
                if (row < N) {
                    float v = acc[mt][jt][r] + b;
                    if (do_relu) v = fmaxf(v, 0.f);
                    outh[(size_t)row * H + col] = __float2half(v);
                }
            }
        }
    }
}

// ---------------- node heads: raw-f16 A, fused W2 reduction --------------------
__global__ __launch_bounds__(256) void node_head_mfma_kernel(
    const __half* __restrict__ x,
    const unsigned short* __restrict__ Wh, const unsigned short* __restrict__ Wl,
    const float* __restrict__ bias256, const float* __restrict__ w2vec,
    const float* __restrict__ b2r, const float* __restrict__ b2a,
    float* __restrict__ out_p, float* __restrict__ out_nl, int N, int row_tiles) {
    const int tid = threadIdx.x;
    const int lane = tid & 63;
    const int wid = blockIdx.x * 4 + (tid >> 6);
    if (wid >= row_tiles) return;
    const int m = lane & 15, quad = lane >> 4;
    const int row0 = wid * 16;

    f32x4v acc[16];
#pragma unroll
    for (int jt = 0; jt < 16; ++jt) acc[jt] = (f32x4v){0.f, 0.f, 0.f, 0.f};

#pragma unroll
    for (int c = 0; c < 4; ++c) {
        int row = row0 + m;
        s16x8 ar = (row < N) ? *(const s16x8*)&x[(size_t)row * H + c * 32 + quad * 8]
                             : (s16x8){0, 0, 0, 0, 0, 0, 0, 0};
        s16x8 ab = h8_to_bf8(ar);
#pragma unroll
        for (int jt = 0; jt < 16; ++jt) {
            const size_t fo = ((size_t)(c * 16 + jt) * 64 + lane) * 8;
            s16x8 bh = *(const s16x8*)&Wh[fo];
            s16x8 bl = *(const s16x8*)&Wl[fo];
            acc[jt] = mfma_h(ar, bh, acc[jt]);
            acc[jt] = __builtin_amdgcn_mfma_f32_16x16x32_bf16(ab, bl, acc[jt], 0, 0, 0);
        }
    }
    float sr[4] = {0.f, 0.f, 0.f, 0.f}, sa[4] = {0.f, 0.f, 0.f, 0.f};
#pragma unroll
    for (int jt = 0; jt < 16; ++jt) {
        int col = jt * 16 + m;
        float b1 = bias256[col];
        float w2 = w2vec[col];
#pragma unroll
        for (int r = 0; r < 4; ++r) {
            float h = fmaxf(acc[jt][r] + b1, 0.f) * w2;
            if (jt < 8) sr[r] += h; else sa[r] += h;
        }
    }
#pragma unroll
    for (int r = 0; r < 4; ++r) {
#pragma unroll
        for (int off = 1; off < 16; off <<= 1) {
            sr[r] += __shfl_xor(sr[r], off);
            sa[r] += __shfl_xor(sa[r], off);
        }
    }
    if (m == 0) {
        float br = b2r[0], ba = b2a[0];
#pragma unroll
        for (int r = 0; r < 4; ++r) {
            int row = row0 + quad * 4 + r;
            if (row < N) {
                out_p[row] = sr[r] + br;
                out_nl[row] = sa[r] + ba;
            }
        }
    }
}

// ---------------- edge-head GEMM: LDS A tile (f16 + bf16 planes) ---------------
__global__ __launch_bounds__(256) void edge_gemm_kernel(
    const __half* __restrict__ xh,
    const unsigned short* __restrict__ Wh, const unsigned short* __restrict__ Wl,
    const float* __restrict__ bias512, __half* __restrict__ P, int N) {
    __shared__ unsigned short sMem[2][64][136];   // [0]=raw f16 A, [1]=bf16(A); later overlaid with C tile
    const int rt = blockIdx.x >> 1, ch = blockIdx.x & 1;
    const int tid = threadIdx.x;
    {
        int row = tid >> 2;
        int k0 = (tid & 3) * 32;
        int gr = rt * 64 + row;
#pragma unroll
        for (int i = 0; i < 4; ++i) {
            int k = k0 + i * 8;
            s16x8 raw = (gr < N) ? *(const s16x8*)&xh[(size_t)gr * H + k]
                                 : (s16x8){0, 0, 0, 0, 0, 0, 0, 0};
            *(s16x8*)&sMem[0][row][k] = raw;
            *(s16x8*)&sMem[1][row][k] = h8_to_bf8(raw);
        }
    }
    __syncthreads();
    const int lane = tid & 63, w = tid >> 6;
    const int m = lane & 15, quad = lane >> 4;

    f32x4v acc[4][4];
#pragma unroll
    for (int mt = 0; mt < 4; ++mt)
#pragma unroll
        for (int jt = 0; jt < 4; ++jt) acc[mt][jt] = (f32x4v){0.f, 0.f, 0.f, 0.f};

#pragma unroll
    for (int c = 0; c < 4; ++c) {
        s16x8 ah[4], ab[4];
#pragma unroll
        for (int mt = 0; mt < 4; ++mt) {
            ah[mt] = *(const s16x8*)&sMem[0][mt * 16 + m][c * 32 + quad * 8];
            ab[mt] = *(const s16x8*)&sMem[1][mt * 16 + m][c * 32 + quad * 8];
        }
#pragma unroll
        for (int jt = 0; jt < 4; ++jt) {
            const int jts = ch * 16 + w * 4 + jt;
            const size_t fo = ((size_t)(c * 32 + jts) * 64 + lane) * 8;
            s16x8 bh = *(const s16x8*)&Wh[fo];
            s16x8 bl = *(const s16x8*)&Wl[fo];
#pragma unroll
            for (int mt = 0; mt < 4; ++mt) {
                acc[mt][jt] = mfma_h(ah[mt], bh, acc[mt][jt]);
                acc[mt][jt] = __builtin_amdgcn_mfma_f32_16x16x32_bf16(ab[mt], bl, acc[mt][jt], 0, 0, 0);
            }
        }
    }
    __syncthreads();   // all A reads complete before overlay
    __half* stage = (__half*)sMem;   // 34816 B >= 32768 B
#pragma unroll
    for (int jt = 0; jt < 4; ++jt) {
        int col = (w * 4 + jt) * 16 + m;   // local col 0..255
        float b = bias512[ch * 256 + col];
#pragma unroll
        for (int mt = 0; mt < 4; ++mt) {
#pragma unroll
            for (int r = 0; r < 4; ++r) {
                int rowl = mt * 16 + quad * 4 + r;
                stage[rowl * 256 + col] = __float2half(acc[mt][jt][r] + b);
            }
        }
    }
    __syncthreads();
#pragma unroll
    for (int it = 0; it < 8; ++it) {
        int idx = it * 256 + tid;          // 0..2047, each = 8 halves
        int rowl = idx >> 5;
        int colh = (idx & 31) * 8;
        int gr = rt * 64 + rowl;
        if (gr < N) {
            *(float4*)&P[(size_t)gr * 512 + ch * 256 + colh] =
                *(const float4*)&stage[rowl * 256 + colh];
        }
    }
}

// ---------------- fused edge epilogue: packed-fp16 hot loop --------------------
__global__ __launch_bounds__(256) void edge_out_fused3_kernel(
    const __half* __restrict__ P, const float4* __restrict__ edataA,
    const int2* __restrict__ edataB,
    const float* __restrict__ erW1, const float* __restrict__ erW2,
    const float* __restrict__ erb2,
    const float* __restrict__ eaW1, const float* __restrict__ eaW2,
    const float* __restrict__ eab2,
    float* __restrict__ out_q, float* __restrict__ out_el, int E) {
    const int lane = threadIdx.x & 63;
    const int half = lane >> 5, th = lane & 31;
    const int head = th >> 4;
    const int d0 = (th & 15) * 8;
    const long hw = ((long)blockIdx.x * 4 + (threadIdx.x >> 6)) * 2 + half;

    const float* W1 = head ? eaW1 : erW1;
    const float* W2 = head ? eaW2 : erW2;
    __half2 wch[6][4];
#pragma unroll
    for (int j = 0; j < 6; j++) {
        float4 t0 = *(const float4*)&W1[(256 + j) * H + d0];
        float4 t1 = *(const float4*)&W1[(256 + j) * H + d0 + 4];
        wch[j][0] = __floats2half2_rn(t0.x, t0.y);
        wch[j][1] = __floats2half2_rn(t0.z, t0.w);
        wch[j][2] = __floats2half2_rn(t1.x, t1.y);
        wch[j][3] = __floats2half2_rn(t1.z, t1.w);
    }
    __half2 w2h[4];
    {
        float4 t0 = *(const float4*)&W2[d0];
        float4 t1 = *(const float4*)&W2[d0 + 4];
        w2h[0] = __floats2half2_rn(t0.x, t0.y);
        w2h[1] = __floats2half2_rn(t0.z, t0.w);
        w2h[2] = __floats2half2_rn(t1.x, t1.y);
        w2h[3] = __floats2half2_rn(t1.z, t1.w);
    }
    const float b2 = head ? eab2[0] : erb2[0];

    union F4H { float4 f; __half2 h[4]; };
    const long j0 = hw * 4;
#pragma unroll
    for (int it = 0; it < 4; ++it) {
        long jj = j0 + it;
        if (jj < E) {
            F4H r0;
            r0.f = edataA[jj];
            int2 de = edataB[jj];
            int s = __float_as_int(r0.f.w);
            int d = de.x;
            int e = de.y;
            __half2 esx = __low2half2(r0.h[0]);
            __half2 esy = __high2half2(r0.h[0]);
            __half2 esz = __low2half2(r0.h[1]);
            __half2 esw = __high2half2(r0.h[1]);
            __half2 qoh = __low2half2(r0.h[2]);
            __half2 qmh = __high2half2(r0.h[2]);
            F4H sv, dv;
            sv.f = *(const float4*)&P[(size_t)s * 512 + th * 8];
            dv.f = *(const float4*)&P[(size_t)d * 512 + 256 + th * 8];
            float part = 0.f;
#pragma unroll
            for (int q = 0; q < 4; ++q) {
                __half2 hid = sv.h[q] + dv.h[q];
                hid = __hfma2(esx, wch[0][q], hid);
                hid = __hfma2(esy, wch[1][q], hid);
                hid = __hfma2(esz, wch[2][q], hid);
                hid = __hfma2(esw, wch[3][q], hid);
                hid = __hfma2(qoh, wch[4][q], hid);
                hid = __hfma2(qmh, wch[5][q], hid);
                hid = relu2(hid);
                part = fdot2f(hid, w2h[q], part);
            }
#pragma unroll
            for (int off = 1; off < 16; off <<= 1) part += __shfl_xor(part, off);
            if ((th & 15) == 0) {
                if (head == 0) out_q[e] = part + b2;
                else out_el[e] = part + b2;
            }
        }
    }
}

// ------------------------------------------------------------------------------
extern "C" void kernel_launch(void* const* d_in, const int* in_sizes, int n_in,
                              void* d_out, int out_size, void* d_ws, size_t ws_size,
                              hipStream_t stream) {
    const int* eidx = (const int*)d_in[0];
    const float* node_static = (const float*)d_in[1];
    const float* edge_static = (const float*)d_in[2];
    const float* p_obs = (const float*)d_in[3];
    const float* q_obs = (const float*)d_in[4];
    const int* p_mask = (const int*)d_in[5];
    const int* q_mask = (const int*)d_in[6];
    const float* W_enc = (const float*)d_in[7];
    const float* b_enc = (const float*)d_in[8];
    const float* W_self = (const float*)d_in[9];
    const float* W_neigh = (const float*)d_in[10];
    const float* b_gnn = (const float*)d_in[11];
    const float* nrW1 = (const float*)d_in[12]; const float* nrb1 = (const float*)d_in[13];
    const float* nrW2 = (const float*)d_in[14]; const float* nrb2 = (const float*)d_in[15];
    const float* naW1 = (const float*)d_in[16]; const float* nab1 = (const float*)d_in[17];
    const float* naW2 = (const float*)d_in[18]; const float* nab2 = (const float*)d_in[19];
    const float* erW1 = (const float*)d_in[20]; const float* erb1 = (const float*)d_in[21];
    const float* erW2 = (const float*)d_in[22]; const float* erb2 = (const float*)d_in[23];
    const float* eaW1 = (const float*)d_in[24]; const float* eab1 = (const float*)d_in[25];
    const float* eaW2 = (const float*)d_in[26]; const float* eab2 = (const float*)d_in[27];

    const int E = in_sizes[0] / 2;
    const int N = in_sizes[3];
    const int* src = eidx;
    const int* dst = eidx + E;

    float* out = (float*)d_out;
    float* p_hat = out;
    float* q_hat = out + N;
    float* node_logits = out + N + E;
    float* edge_logits = out + 2 * N + E;

    __half* xh0 = (__half*)d_ws;               // [N,128] f16
    __half* xh1 = xh0 + (size_t)N * H;         // [N,128] f16
    __half* P = xh1 + (size_t)N * H;           // [N,512] f16
    float4* edataA = (float4*)(P + (size_t)N * 512);   // E x 16 B
    int2* edataB = (int2*)(edataA + (size_t)E);        // E x 8 B
    int2* padj = (int2*)(edataB + (size_t)E);          // [N,SLOT] (dst, e)
    int* adj_in = (int*)(padj + (size_t)N * SLOT);     // [N,SLOT]
    int* cur_o = adj_in + (size_t)N * SLOT;    // N
    int* cur_i = cur_o + N;                    // N
    int* rowptr2 = cur_i + N;                  // N
    int* bsum = rowptr2 + N;                   // 512
    unsigned short* WLh = (unsigned short*)(bsum + 512);   // 3*32768
    unsigned short* WLl = WLh + 3 * 32768;
    unsigned short* WEh = WLl + 3 * 32768;     // 65536
    unsigned short* WEl = WEh + 65536;
    unsigned short* WNh = WEl + 65536;         // 32768
    unsigned short* WNl = WNh + 32768;
    float* bias512 = (float*)(WNl + 32768);    // 512
    float* bias_nd = bias512 + 512;            // 256
    float* w2_nd = bias_nd + 256;              // 256

    const int NB = (N + 255) / 256;
    const int RT32 = (N + 31) / 32;
    const int RT16 = (N + 15) / 16;
    const int RT64 = (N + 63) / 64;

    const int quarter = (E + 3) / 4;
    const int FB = (quarter + 255) / 256;
    const int ENCB = (N * H + 255) / 256;

    hipMemsetAsync(cur_o, 0, (size_t)2 * N * sizeof(int), stream);
    pre_kernel<<<FB + 768 + ENCB, 256, 0, stream>>>(
        src, dst, cur_o, cur_i, padj, adj_in, E, quarter, FB,
        W_self, W_neigh, WLh, WLl,
        erW1, erb1, eaW1, eab1, WEh, WEl, bias512,
        nrW1, naW1, nrb1, nab1, nrW2, naW2, WNh, WNl, bias_nd, w2_nd,
        node_static, p_obs, p_mask, W_enc, b_enc, xh0, N);
    bsum_kernel<<<NB, 256, 0, stream>>>(cur_o, bsum, N);
    scan_bsum_kernel<<<1, 512, 0, stream>>>(bsum, NB);
    rowptr_kernel<<<NB, 256, 0, stream>>>(cur_o, bsum, rowptr2, N);
    compact_kernel<<<(4 * N + 255) / 256, 256, 0, stream>>>(
        padj, cur_o, rowptr2, edge_static, q_obs, q_mask, edataA, edataB, N);

    __half* cur = xh0;
    __half* other = xh1;
    for (int l = 0; l < 3; ++l) {
        gather_h_kernel<<<(N + 15) / 16, 256, 0, stream>>>(cur_o, cur_i, padj, adj_in,
                                                           cur, other, N);
        layer_gemm_kernel<<<(RT32 + 3) / 4, 256, 0, stream>>>(
            cur, other, WLh + (size_t)l * 32768, WLl + (size_t)l * 32768,
            b_gnn + l * H, other, N, (l < 2) ? 1 : 0, RT32);
        __half* t = cur; cur = other; other = t;
    }

    node_head_mfma_kernel<<<(RT16 + 3) / 4, 256, 0, stream>>>(
        cur, WNh, WNl, bias_nd, w2_nd, nrb2, nab2, p_hat, node_logits, N, RT16);

    edge_gemm_kernel<<<RT64 * 2, 256, 0, stream>>>(cur, WEh, WEl, bias512, P, N);
    edge_out_fused3_kernel<<<(E + 31) / 32, 256, 0, stream>>>(
        P, edataA, edataB, erW1, erW2, erb2, eaW1, eaW2, eab2, q_hat, edge_logits, E);
}